// Round 2
// baseline (114.635 us; speedup 1.0000x reference)
//
#include <hip/hip_runtime.h>
#include <hip/hip_bf16.h>

// Problem constants
#define T_ 8192
#define H_ 64
#define X_ 128
#define C_ 128   // number of chunks
#define L_ 64    // chunk length (C_*L_ == T_)
#define K1_TB 16 // t-rows per block in the b-projection kernel

// ---------------------------------------------------------------------------
// One recurrence step: newh[i] = sum_j arow[j]*h[j] + b_i.
// h is lane-distributed (lane j holds h[j]). Broadcast via LDS: each lane
// writes its h, one barrier (1-wave block: cheap), then all lanes read the
// full row with same-address float4 reads (HW broadcast, conflict-free).
// arow[] must be compile-time indexed (registers).
// ---------------------------------------------------------------------------
__device__ __forceinline__ float lru_step_lds(const float* arow, float h, float b_i,
                                              float* hsbuf, int lane) {
    hsbuf[lane] = h;
    __syncthreads();
    const float4* h4 = (const float4*)hsbuf;
    float a0 = b_i, a1 = 0.f, a2 = 0.f, a3 = 0.f;
#pragma unroll
    for (int q = 0; q < 16; ++q) {
        float4 hv = h4[q];
        a0 = fmaf(arow[4 * q + 0], hv.x, a0);
        a1 = fmaf(arow[4 * q + 1], hv.y, a1);
        a2 = fmaf(arow[4 * q + 2], hv.z, a2);
        a3 = fmaf(arow[4 * q + 3], hv.w, a3);
    }
    return (a0 + a1) + (a2 + a3);
}

// Build row `lane` of A = 0.9*I + 0.1*A_raw into registers.
__device__ __forceinline__ void load_arow_A(const float* __restrict__ A_raw,
                                            int lane, float* arow) {
    const float4* a4 = (const float4*)(A_raw + lane * H_);
#pragma unroll
    for (int q = 0; q < 16; ++q) {
        float4 t4 = a4[q];
        arow[4 * q + 0] = 0.1f * t4.x;
        arow[4 * q + 1] = 0.1f * t4.y;
        arow[4 * q + 2] = 0.1f * t4.z;
        arow[4 * q + 3] = 0.1f * t4.w;
    }
#pragma unroll
    for (int q = 0; q < 64; ++q) arow[q] += (q == lane) ? 0.9f : 0.0f;
}

// ---------------------------------------------------------------------------
// K1: b[t][h] = sum_x x[t][x] * B[h][x] + c[h]  -> written into d_out.
// No LDS: lane = h; B row chunk (32 floats) lives in registers; x rows are
// read via wave-uniform addresses (scalar-load path); 4 t-rows per thread.
// ---------------------------------------------------------------------------
__global__ __launch_bounds__(256) void k_bproj(const float* __restrict__ x,
                                               const float* __restrict__ B,
                                               const float* __restrict__ c,
                                               float* __restrict__ b_out) {
    const int lane = threadIdx.x & 63;
    const int w    = __builtin_amdgcn_readfirstlane(threadIdx.x >> 6);  // 0..3
    const int t0   = blockIdx.x * K1_TB + w * 4;  // this wave's 4 t-rows

    const float cc = c[lane];
    float acc[4];
#pragma unroll
    for (int r = 0; r < 4; ++r) acc[r] = cc;

    const float* Brow = B + lane * X_;
#pragma unroll
    for (int kc = 0; kc < 4; ++kc) {
        float4 br[8];
        const float4* b4 = (const float4*)(Brow + kc * 32);
#pragma unroll
        for (int q = 0; q < 8; ++q) br[q] = b4[q];
#pragma unroll
        for (int r = 0; r < 4; ++r) {
            const float4* xr = (const float4*)(x + (size_t)(t0 + r) * X_ + kc * 32);
#pragma unroll
            for (int q = 0; q < 8; ++q) {
                float4 xv = xr[q];
                acc[r] = fmaf(br[q].x, xv.x, acc[r]);
                acc[r] = fmaf(br[q].y, xv.y, acc[r]);
                acc[r] = fmaf(br[q].z, xv.z, acc[r]);
                acc[r] = fmaf(br[q].w, xv.w, acc[r]);
            }
        }
    }
#pragma unroll
    for (int r = 0; r < 4; ++r) {
        b_out[(size_t)(t0 + r) * H_ + lane] = acc[r];
    }
}

// ---------------------------------------------------------------------------
// K2: blocks 0..C_-1: chunk-local recurrence from zero state -> v[c][:]
//     blocks C_..C_+H_-1: column (wid-C_) of A^L via recurrence on e_col -> AL
// ---------------------------------------------------------------------------
__global__ __launch_bounds__(64) void k_phase1(const float* __restrict__ A_raw,
                                               const float* __restrict__ b,
                                               float* __restrict__ v,
                                               float* __restrict__ AL) {
    __shared__ __align__(16) float hs[2][H_];
    const int lane = threadIdx.x;
    const int wid  = blockIdx.x;
    float arow[64];
    load_arow_A(A_raw, lane, arow);

    if (wid < C_) {
        const float* bc = b + (size_t)wid * L_ * H_ + lane;
        float h = 0.f;
        float bnext = bc[0];
#pragma unroll 2
        for (int t = 0; t < L_; ++t) {
            const float bi = bnext;
            if (t + 1 < L_) bnext = bc[(size_t)(t + 1) * H_];
            h = lru_step_lds(arow, h, bi, hs[t & 1], lane);
        }
        v[wid * H_ + lane] = h;
    } else {
        const int col = wid - C_;
        float h = (lane == col) ? 1.f : 0.f;
#pragma unroll 2
        for (int t = 0; t < L_; ++t) {
            h = lru_step_lds(arow, h, 0.f, hs[t & 1], lane);
        }
        AL[lane * H_ + col] = h;  // row-major A^L
    }
}

// ---------------------------------------------------------------------------
// K3: serial scan over chunks with A^L: hstart[c] = state before chunk c.
// ---------------------------------------------------------------------------
__global__ __launch_bounds__(64) void k_phase2(const float* __restrict__ AL,
                                               const float* __restrict__ h0,
                                               const float* __restrict__ v,
                                               float* __restrict__ hstart) {
    __shared__ __align__(16) float hs[2][H_];
    const int lane = threadIdx.x;
    float arow[64];
    const float4* a4 = (const float4*)(AL + lane * H_);
#pragma unroll
    for (int q = 0; q < 16; ++q) {
        float4 t4 = a4[q];
        arow[4 * q + 0] = t4.x;
        arow[4 * q + 1] = t4.y;
        arow[4 * q + 2] = t4.z;
        arow[4 * q + 3] = t4.w;
    }
    float h = h0[lane];
    float vnext = v[lane];
#pragma unroll 2
    for (int c = 0; c < C_; ++c) {
        hstart[c * H_ + lane] = h;
        const float vi = vnext;
        if (c + 1 < C_) vnext = v[(c + 1) * H_ + lane];
        h = lru_step_lds(arow, h, vi, hs[c & 1], lane);
    }
}

// ---------------------------------------------------------------------------
// K4: replay each chunk from hstart, overwriting b rows in d_out with h rows.
// ---------------------------------------------------------------------------
__global__ __launch_bounds__(64) void k_phase3(const float* __restrict__ A_raw,
                                               const float* __restrict__ hstart,
                                               float* __restrict__ out) {
    __shared__ __align__(16) float hs[2][H_];
    const int lane = threadIdx.x;
    const int cid  = blockIdx.x;
    float arow[64];
    load_arow_A(A_raw, lane, arow);

    float h = hstart[cid * H_ + lane];
    float* oc = out + (size_t)cid * L_ * H_ + lane;
    float bnext = oc[0];
#pragma unroll 2
    for (int t = 0; t < L_; ++t) {
        const float bi = bnext;
        if (t + 1 < L_) bnext = oc[(size_t)(t + 1) * H_];
        h = lru_step_lds(arow, h, bi, hs[t & 1], lane);
        oc[(size_t)t * H_] = h;
    }
}

extern "C" void kernel_launch(void* const* d_in, const int* in_sizes, int n_in,
                              void* d_out, int out_size, void* d_ws, size_t ws_size,
                              hipStream_t stream) {
    const float* x     = (const float*)d_in[0];  // [T, X]
    const float* h0    = (const float*)d_in[1];  // [H]
    const float* A_raw = (const float*)d_in[2];  // [H, H]
    const float* B     = (const float*)d_in[3];  // [H, X]
    const float* c     = (const float*)d_in[4];  // [H]
    float* out = (float*)d_out;                  // [T, H]; reused as b storage
    float* ws  = (float*)d_ws;

    float* AL     = ws;                 // H_*H_ = 4096 floats
    float* v      = ws + 4096;          // C_*H_ = 8192 floats
    float* hstart = ws + 4096 + 8192;   // C_*H_ = 8192 floats

    k_bproj <<<T_ / K1_TB, 256, 0, stream>>>(x, B, c, out);
    k_phase1<<<C_ + H_,    64,  0, stream>>>(A_raw, out, v, AL);
    k_phase2<<<1,          64,  0, stream>>>(AL, h0, v, hstart);
    k_phase3<<<C_,         64,  0, stream>>>(A_raw, hstart, out);
}

// Round 3
// 82.411 us; speedup vs baseline: 1.3910x; 1.3910x over previous
//
#include <hip/hip_runtime.h>
#include <hip/hip_bf16.h>

// Problem constants
#define T_ 8192
#define H_ 64
#define X_ 128
#define C_ 128   // number of chunks
#define L_ 64    // chunk length (C_*L_ == T_)
#define K1_TB 16 // t-rows per block in the b-projection kernel

// ---------------------------------------------------------------------------
// Broadcast a float from lane `src` (compile-time constant) to all lanes.
__device__ __forceinline__ float bcast(float v, int src) {
    return __int_as_float(__builtin_amdgcn_readlane(__float_as_int(v), src));
}

// One recurrence step: newh[i] = sum_j arow[j]*h[j] + b_i, h lane-distributed.
// Readlane broadcast (round-1 proven form; ~650cyc latency, ~260cyc issue).
__device__ __forceinline__ float lru_step(const float* arow, float h, float b_i) {
    float a0 = b_i, a1 = 0.f, a2 = 0.f, a3 = 0.f;
#pragma unroll
    for (int j = 0; j < 16; ++j) {
        a0 = fmaf(arow[j],      bcast(h, j),      a0);
        a1 = fmaf(arow[j + 16], bcast(h, j + 16), a1);
        a2 = fmaf(arow[j + 32], bcast(h, j + 32), a2);
        a3 = fmaf(arow[j + 48], bcast(h, j + 48), a3);
    }
    return (a0 + a1) + (a2 + a3);
}

// Force a 64-float row to live in VGPRs (guard against scratch/reload).
__device__ __forceinline__ void pin_row(float* arow) {
#pragma unroll
    for (int q = 0; q < 64; ++q) asm volatile("" : "+v"(arow[q]));
}

// Build row `lane` of A = 0.9*I + 0.1*A_raw into registers.
__device__ __forceinline__ void load_arow_A(const float* __restrict__ A_raw,
                                            int lane, float* arow) {
    const float4* a4 = (const float4*)(A_raw + lane * H_);
#pragma unroll
    for (int q = 0; q < 16; ++q) {
        float4 t4 = a4[q];
        arow[4 * q + 0] = 0.1f * t4.x;
        arow[4 * q + 1] = 0.1f * t4.y;
        arow[4 * q + 2] = 0.1f * t4.z;
        arow[4 * q + 3] = 0.1f * t4.w;
    }
#pragma unroll
    for (int q = 0; q < 64; ++q) arow[q] += (q == lane) ? 0.9f : 0.0f;
    pin_row(arow);
}

// Load row `lane` of a row-major [64][64] matrix into registers.
__device__ __forceinline__ void load_row(const float* __restrict__ M,
                                         int lane, float* arow) {
    const float4* a4 = (const float4*)(M + lane * H_);
#pragma unroll
    for (int q = 0; q < 16; ++q) {
        float4 t4 = a4[q];
        arow[4 * q + 0] = t4.x;
        arow[4 * q + 1] = t4.y;
        arow[4 * q + 2] = t4.z;
        arow[4 * q + 3] = t4.w;
    }
    pin_row(arow);
}

// ---------------------------------------------------------------------------
// K_A: blocks 0..511: b[t][h] = sum_x x[t][x]*B[h][x] + c[h] -> bws
//      block 512: A2 = A*A, A4 = A2*A2, A8 = A4*A4 (in-block LDS matmuls)
// ---------------------------------------------------------------------------
#define PSTR 68  // LDS row stride (floats): 16B-aligned rows, bank-staggered
__global__ __launch_bounds__(256) void k_bproj_pow(
        const float* __restrict__ x, const float* __restrict__ A_raw,
        const float* __restrict__ B, const float* __restrict__ c,
        float* __restrict__ bws, float* __restrict__ A2g,
        float* __restrict__ A4g, float* __restrict__ A8g) {
    __shared__ float M1[H_ * PSTR];
    __shared__ float M2[H_ * PSTR];
    const int tid = threadIdx.x;

    if (blockIdx.x < T_ / K1_TB) {
        // ---- b projection (round-2 proven) ----
        const int lane = tid & 63;
        const int w    = __builtin_amdgcn_readfirstlane(tid >> 6);
        const int t0   = blockIdx.x * K1_TB + w * 4;
        const float cc = c[lane];
        float acc[4];
#pragma unroll
        for (int r = 0; r < 4; ++r) acc[r] = cc;
        const float* Brow = B + lane * X_;
#pragma unroll
        for (int kc = 0; kc < 4; ++kc) {
            float4 br[8];
            const float4* b4 = (const float4*)(Brow + kc * 32);
#pragma unroll
            for (int q = 0; q < 8; ++q) br[q] = b4[q];
#pragma unroll
            for (int r = 0; r < 4; ++r) {
                const float4* xr = (const float4*)(x + (size_t)(t0 + r) * X_ + kc * 32);
#pragma unroll
                for (int q = 0; q < 8; ++q) {
                    float4 xv = xr[q];
                    acc[r] = fmaf(br[q].x, xv.x, acc[r]);
                    acc[r] = fmaf(br[q].y, xv.y, acc[r]);
                    acc[r] = fmaf(br[q].z, xv.z, acc[r]);
                    acc[r] = fmaf(br[q].w, xv.w, acc[r]);
                }
            }
        }
#pragma unroll
        for (int r = 0; r < 4; ++r) bws[(size_t)(t0 + r) * H_ + lane] = acc[r];
        return;
    }

    // ---- powers block ----
    for (int idx = tid; idx < H_ * H_; idx += 256) {
        const int r = idx >> 6, cc = idx & 63;
        M1[r * PSTR + cc] = 0.1f * A_raw[idx] + ((r == cc) ? 0.9f : 0.0f);
    }
    __syncthreads();

    const int r = tid >> 2;          // 0..63
    const int q = tid & 3;           // col block of 16
    const int c0 = q * 16;

    // mm #1: M2 = M1*M1 ; global A2
    {
        float acc[16];
#pragma unroll
        for (int j = 0; j < 16; ++j) acc[j] = 0.f;
        for (int k = 0; k < H_; ++k) {
            const float m1 = M1[r * PSTR + k];
            const float4* s2 = (const float4*)&M1[k * PSTR + c0];
#pragma unroll
            for (int j4 = 0; j4 < 4; ++j4) {
                float4 bv = s2[j4];
                acc[4 * j4 + 0] = fmaf(m1, bv.x, acc[4 * j4 + 0]);
                acc[4 * j4 + 1] = fmaf(m1, bv.y, acc[4 * j4 + 1]);
                acc[4 * j4 + 2] = fmaf(m1, bv.z, acc[4 * j4 + 2]);
                acc[4 * j4 + 3] = fmaf(m1, bv.w, acc[4 * j4 + 3]);
            }
        }
#pragma unroll
        for (int j = 0; j < 16; ++j) {
            M2[r * PSTR + c0 + j] = acc[j];
            A2g[r * H_ + c0 + j]  = acc[j];
        }
    }
    __syncthreads();
    // mm #2: M1 = M2*M2 ; global A4
    {
        float acc[16];
#pragma unroll
        for (int j = 0; j < 16; ++j) acc[j] = 0.f;
        for (int k = 0; k < H_; ++k) {
            const float m1 = M2[r * PSTR + k];
            const float4* s2 = (const float4*)&M2[k * PSTR + c0];
#pragma unroll
            for (int j4 = 0; j4 < 4; ++j4) {
                float4 bv = s2[j4];
                acc[4 * j4 + 0] = fmaf(m1, bv.x, acc[4 * j4 + 0]);
                acc[4 * j4 + 1] = fmaf(m1, bv.y, acc[4 * j4 + 1]);
                acc[4 * j4 + 2] = fmaf(m1, bv.z, acc[4 * j4 + 2]);
                acc[4 * j4 + 3] = fmaf(m1, bv.w, acc[4 * j4 + 3]);
            }
        }
        __syncthreads();  // all reads of M2 done before overwriting M1? (M1 is dst, M2 src: safe) -- barrier before M1 reuse below
#pragma unroll
        for (int j = 0; j < 16; ++j) {
            M1[r * PSTR + c0 + j] = acc[j];
            A4g[r * H_ + c0 + j]  = acc[j];
        }
    }
    __syncthreads();
    // mm #3: A8 = M1*M1 (global only)
    {
        float acc[16];
#pragma unroll
        for (int j = 0; j < 16; ++j) acc[j] = 0.f;
        for (int k = 0; k < H_; ++k) {
            const float m1 = M1[r * PSTR + k];
            const float4* s2 = (const float4*)&M1[k * PSTR + c0];
#pragma unroll
            for (int j4 = 0; j4 < 4; ++j4) {
                float4 bv = s2[j4];
                acc[4 * j4 + 0] = fmaf(m1, bv.x, acc[4 * j4 + 0]);
                acc[4 * j4 + 1] = fmaf(m1, bv.y, acc[4 * j4 + 1]);
                acc[4 * j4 + 2] = fmaf(m1, bv.z, acc[4 * j4 + 2]);
                acc[4 * j4 + 3] = fmaf(m1, bv.w, acc[4 * j4 + 3]);
            }
        }
#pragma unroll
        for (int j = 0; j < 16; ++j) A8g[r * H_ + c0 + j] = acc[j];
    }
}

// ---------------------------------------------------------------------------
// K_B: b~8_t = sum_{j=0..min(7, i)} A^j b_{t-j}  (i = t&63, chunk-clamped)
// via log-doubling: d2 = b + A b_-1 ; d4 = d2 + A2 d2_-2 ; d8 = d4 + A4 d4_-4
// Throughput-bound: matrix row in regs, x-vectors broadcast from LDS.
// ---------------------------------------------------------------------------
#define KB_ROWS 23  // 16 output rows + 7 halo
__global__ __launch_bounds__(256) void k_btilde(
        const float* __restrict__ A_raw, const float* __restrict__ A2,
        const float* __restrict__ A4, const float* __restrict__ bsrc,
        float* __restrict__ bt8) {
    __shared__ __align__(16) float buf[2][KB_ROWS][H_];
    const int tid = threadIdx.x, lane = tid & 63, w = tid >> 6;
    const int t0 = blockIdx.x * K1_TB;

    for (int idx = tid; idx < KB_ROWS * H_; idx += 256) {
        const int row = idx >> 6, hh = idx & 63;
        const int t = t0 - 7 + row;
        buf[0][row][hh] = (t >= 0) ? bsrc[(size_t)t * H_ + hh] : 0.f;
    }
    __syncthreads();

    int src = 0;
    float arow[64];
#pragma unroll
    for (int pass = 0; pass < 3; ++pass) {
        const int dist = 1 << pass;
        if (pass == 0)      load_arow_A(A_raw, lane, arow);
        else if (pass == 1) load_row(A2, lane, arow);
        else                load_row(A4, lane, arow);
        for (int row = w; row < KB_ROWS; row += 4) {
            const int t = t0 - 7 + row;
            float val = buf[src][row][lane];
            if (row >= dist && t >= 0 && (t & 63) >= dist) {
                const float4* h4 = (const float4*)buf[src][row - dist];
                float a0 = val, a1 = 0.f, a2 = 0.f, a3 = 0.f;
#pragma unroll
                for (int qq = 0; qq < 16; ++qq) {
                    float4 hv = h4[qq];
                    a0 = fmaf(arow[4 * qq + 0], hv.x, a0);
                    a1 = fmaf(arow[4 * qq + 1], hv.y, a1);
                    a2 = fmaf(arow[4 * qq + 2], hv.z, a2);
                    a3 = fmaf(arow[4 * qq + 3], hv.w, a3);
                }
                val = (a0 + a1) + (a2 + a3);
            }
            buf[src ^ 1][row][lane] = val;
        }
        __syncthreads();
        src ^= 1;
    }
    for (int r2 = w; r2 < 16; r2 += 4) {
        bt8[(size_t)(t0 + r2) * H_ + lane] = buf[src][7 + r2][lane];
    }
}

// ---------------------------------------------------------------------------
// K_C: blocks 0..127: v_c (chunk-local end state) via head b~8_7 + 7 A^8 steps
//      blocks 128..191: column (bid-128) of Q = A^64 via 8 A^8 steps on e_col
// ---------------------------------------------------------------------------
__global__ __launch_bounds__(64) void k_phase1(
        const float* __restrict__ A8, const float* __restrict__ bt8,
        float* __restrict__ v, float* __restrict__ ALQ) {
    const int lane = threadIdx.x, bid = blockIdx.x;
    float arow[64];
    load_row(A8, lane, arow);
    if (bid < C_) {
        const float* bc = bt8 + (size_t)bid * L_ * H_;
        float y = bc[7 * H_ + lane];
#pragma unroll
        for (int k = 1; k <= 7; ++k)
            y = lru_step(arow, y, bc[(size_t)(7 + 8 * k) * H_ + lane]);
        v[bid * H_ + lane] = y;
    } else {
        const int col = bid - C_;
        float y = (lane == col) ? 1.f : 0.f;
#pragma unroll
        for (int k = 0; k < 8; ++k) y = lru_step(arow, y, 0.f);
        ALQ[lane * H_ + col] = y;  // row-major Q
    }
}

// ---------------------------------------------------------------------------
// K_D: blocks 0..63: column col of Q8 = Q^8 via 7 chained Q-matvecs
//      blocks 64..183: vtilde_c = sum_{j=0..7} Q^j v_{c-1-j} (Horner), c=8..127
// ---------------------------------------------------------------------------
__global__ __launch_bounds__(64) void k_prep2(
        const float* __restrict__ ALQ, const float* __restrict__ v,
        float* __restrict__ Q8, float* __restrict__ vt) {
    const int lane = threadIdx.x, bid = blockIdx.x;
    float arow[64];
    load_row(ALQ, lane, arow);  // Q row
    if (bid < H_) {
        const int col = bid;
        float y = ALQ[lane * H_ + col];
#pragma unroll
        for (int k = 0; k < 7; ++k) y = lru_step(arow, y, 0.f);
        Q8[lane * H_ + col] = y;
    } else {
        const int c = bid - H_ + 8;  // 8..127
        float y = v[(c - 8) * H_ + lane];
#pragma unroll
        for (int k = 7; k >= 1; --k)
            y = lru_step(arow, y, v[(c - k) * H_ + lane]);
        vt[c * H_ + lane] = y;
    }
}

// ---------------------------------------------------------------------------
// K_E: chunk-level scan. wave0: serial s_1..s_7 (Q steps); then 8 chains of
// 15 Q^8-steps, 2 chains per wave (ILP-2 hides matvec latency).
// ---------------------------------------------------------------------------
__global__ __launch_bounds__(256) void k_phase2(
        const float* __restrict__ ALQ, const float* __restrict__ Q8,
        const float* __restrict__ h0, const float* __restrict__ v,
        const float* __restrict__ vt, float* __restrict__ hstart) {
    __shared__ __align__(16) float s8[8][H_];
    const int tid = threadIdx.x, lane = tid & 63, w = tid >> 6;
    float arow8[64];
    load_row(Q8, lane, arow8);
    if (w == 0) {
        float arowQ[64];
        load_row(ALQ, lane, arowQ);
        float s = h0[lane];
        hstart[lane] = s;
        s8[0][lane]  = s;
#pragma unroll
        for (int cc = 0; cc < 7; ++cc) {
            s = lru_step(arowQ, s, v[cc * H_ + lane]);
            hstart[(cc + 1) * H_ + lane] = s;
            s8[cc + 1][lane] = s;
        }
    }
    __syncthreads();
    const int r0 = w, r1 = w + 4;
    float y0 = s8[r0][lane], y1 = s8[r1][lane];
#pragma unroll
    for (int k = 1; k <= 15; ++k) {
        const int c0 = r0 + 8 * k, c1 = r1 + 8 * k;
        y0 = lru_step(arow8, y0, vt[c0 * H_ + lane]);
        y1 = lru_step(arow8, y1, vt[c1 * H_ + lane]);
        hstart[c0 * H_ + lane] = y0;
        hstart[c1 * H_ + lane] = y1;
    }
}

// ---------------------------------------------------------------------------
// K_F: replay chunk cid. wave0: serial h_0..h_7 (A steps from s_c); then 8
// chains of 7 A^8-steps (2 per wave) write all remaining rows.
// ---------------------------------------------------------------------------
__global__ __launch_bounds__(256) void k_phase3(
        const float* __restrict__ A_raw, const float* __restrict__ A8,
        const float* __restrict__ hstart, const float* __restrict__ bws,
        const float* __restrict__ bt8, float* __restrict__ out) {
    __shared__ __align__(16) float h8[8][H_];
    const int tid = threadIdx.x, lane = tid & 63, w = tid >> 6;
    const int cid = blockIdx.x;
    float arow8[64];
    load_row(A8, lane, arow8);
    float* oc = out + (size_t)cid * L_ * H_;
    if (w == 0) {
        float arowA[64];
        load_arow_A(A_raw, lane, arowA);
        float y = hstart[cid * H_ + lane];
#pragma unroll
        for (int i = 0; i < 8; ++i) {
            y = lru_step(arowA, y, bws[((size_t)cid * L_ + i) * H_ + lane]);
            oc[(size_t)i * H_ + lane] = y;
            h8[i][lane] = y;
        }
    }
    __syncthreads();
    const int r0 = w, r1 = w + 4;
    float y0 = h8[r0][lane], y1 = h8[r1][lane];
#pragma unroll
    for (int k = 1; k <= 7; ++k) {
        const int i0 = r0 + 8 * k, i1 = r1 + 8 * k;
        y0 = lru_step(arow8, y0, bt8[((size_t)cid * L_ + i0) * H_ + lane]);
        y1 = lru_step(arow8, y1, bt8[((size_t)cid * L_ + i1) * H_ + lane]);
        oc[(size_t)i0 * H_ + lane] = y0;
        oc[(size_t)i1 * H_ + lane] = y1;
    }
}

extern "C" void kernel_launch(void* const* d_in, const int* in_sizes, int n_in,
                              void* d_out, int out_size, void* d_ws, size_t ws_size,
                              hipStream_t stream) {
    const float* x     = (const float*)d_in[0];  // [T, X]
    const float* h0    = (const float*)d_in[1];  // [H]
    const float* A_raw = (const float*)d_in[2];  // [H, H]
    const float* B     = (const float*)d_in[3];  // [H, X]
    const float* c     = (const float*)d_in[4];  // [H]
    float* out = (float*)d_out;                  // [T, H]
    float* ws  = (float*)d_ws;

    float* bws    = ws;                        // T*H
    float* bt8    = bws + T_ * H_;             // T*H
    float* A2     = bt8 + T_ * H_;             // 4096
    float* A4     = A2 + H_ * H_;              // 4096
    float* A8     = A4 + H_ * H_;              // 4096
    float* ALQ    = A8 + H_ * H_;              // 4096 (Q = A^64)
    float* Q8     = ALQ + H_ * H_;             // 4096 (Q^8 = A^512)
    float* v      = Q8 + H_ * H_;              // C*H
    float* vt     = v + C_ * H_;               // C*H
    float* hstart = vt + C_ * H_;              // C*H

    k_bproj_pow<<<T_ / K1_TB + 1, 256, 0, stream>>>(x, A_raw, B, c, bws, A2, A4, A8);
    k_btilde  <<<T_ / K1_TB,     256, 0, stream>>>(A_raw, A2, A4, bws, bt8);
    k_phase1  <<<C_ + H_,        64,  0, stream>>>(A8, bt8, v, ALQ);
    k_prep2   <<<H_ + (C_ - 8),  64,  0, stream>>>(ALQ, v, Q8, vt);
    k_phase2  <<<1,              256, 0, stream>>>(ALQ, Q8, h0, v, vt, hstart);
    k_phase3  <<<C_,             256, 0, stream>>>(A_raw, A8, hstart, bws, bt8, out);
}